// Round 2
// baseline (131.085 us; speedup 1.0000x reference)
//
#include <hip/hip_runtime.h>
#include <stdint.h>

// ---------------------------------------------------------------------------
// R11 restructure: occupancy + de-staging.
//  - grid 1024 (2 blocks per batch elem, 16 i-rows each), 512 thr, pinned to
//    6 waves/SIMD (3 blocks/CU = 24 waves/CU; was 2 blocks / 16 waves).
//  - k_prep pre-transposes ew1/nw1/nw2 to f16 in d_ws (pre-scaled by log2e);
//    per-block transpose dances deleted. en L1/L2 B-frags read direct from L2.
//  - W1^T (ee) lives in LDS (DMA'd via global_load_lds), not 96 VGPRs.
//  - xs_h / ew1T LDS: unpadded [row][256] f16 with 16B-block XOR swizzle
//    (kb ^= row&7) applied at producer AND consumer -> 2-way max conflicts.
// R12: fix MFMA16 builtin spelling via __has_builtin guard (gfx950 ROCm
//    spells it __builtin_amdgcn_mfma_f32_16x16x16f16).
// ---------------------------------------------------------------------------

static constexpr int B_ = 512, N_ = 32, D_ = 256, K_ = 8;
static constexpr int E1 = 40, E2 = 6;          // ee MLP 256->40->6->1
static constexpr int N1 = 81, N2 = 25, N3 = 8; // en MLP 256->81->25->8
static constexpr int HEP = 96;                 // h1e row stride (f16)
static constexpr float LN2f = 0.69314718055994530942f;
static constexpr float L2Ef = 1.44269504088896340736f;

typedef float    f32x4 __attribute__((ext_vector_type(4)));
typedef _Float16 f16x8 __attribute__((ext_vector_type(8)));
typedef _Float16 f16x4 __attribute__((ext_vector_type(4)));

#define MFMA32(A, B, C) __builtin_amdgcn_mfma_f32_16x16x32_f16((A), (B), (C), 0, 0, 0)
#if __has_builtin(__builtin_amdgcn_mfma_f32_16x16x16_f16)
#define MFMA16(A, B, C) __builtin_amdgcn_mfma_f32_16x16x16_f16((A), (B), (C), 0, 0, 0)
#else
#define MFMA16(A, B, C) __builtin_amdgcn_mfma_f32_16x16x16f16((A), (B), (C), 0, 0, 0)
#endif

// base-2 shifted softplus: ssp(x)/ln2 with t = x*log2e (v_log_f32 is log2).
__device__ __forceinline__ float ssp2(float t) {
    float e = __builtin_amdgcn_exp2f(t);
    return __builtin_amdgcn_logf(fmaf(e, 0.5f, 0.5f));
}

__device__ __forceinline__ void lds_dma16(void* lds, const void* g) {
    __builtin_amdgcn_global_load_lds(
        (const __attribute__((address_space(1))) unsigned int*)(uintptr_t)g,
        (__attribute__((address_space(3))) unsigned int*)(uintptr_t)lds,
        16, 0, 0);
}

// ---------------------------------------------------------------------------
// prep kernel: weights -> f16 transposed layouts in workspace (once/launch).
//   ew1T [48][256] f16, *log2e, 16B-block XOR-swizzled (consumed from LDS)
//   nw1T [96][256] f16, *log2e, plain           (consumed from global/L2)
//   nw2T [32][ 96] f16, raw,    plain           (consumed from global/L2)
// ---------------------------------------------------------------------------
__global__ __launch_bounds__(256) void k_prep(
    const float* __restrict__ ew1, const float* __restrict__ nw1,
    const float* __restrict__ nw2, _Float16* __restrict__ wsp)
{
    const int g = blockIdx.x * 256 + threadIdx.x;
    _Float16* ew1T = wsp;
    _Float16* nw1T = wsp + 48 * 256;
    _Float16* nw2T = wsp + 48 * 256 + 96 * 256;

    if (g < 1536) {                         // ew1T: 48 rows x 32 kb
        const int n = g >> 5, kb = g & 31;
        f16x8 v;
        #pragma unroll
        for (int d = 0; d < 8; ++d) {
            const int k = kb * 8 + d;
            v[d] = (_Float16)((n < E1) ? ew1[k * E1 + n] * L2Ef : 0.f);
        }
        *(f16x8*)&ew1T[n * 256 + ((kb ^ (n & 7)) << 3)] = v;
    } else if (g < 4608) {                  // nw1T: 96 rows x 32 kb
        const int q = g - 1536;
        const int n = q >> 5, kb = q & 31;
        f16x8 v;
        #pragma unroll
        for (int d = 0; d < 8; ++d) {
            const int k = kb * 8 + d;
            v[d] = (_Float16)((n < N1) ? nw1[k * N1 + n] * L2Ef : 0.f);
        }
        *(f16x8*)&nw1T[n * 256 + kb * 8] = v;
    } else if (g < 4992) {                  // nw2T: 32 rows x 12 kb (96 k)
        const int q = g - 4608;
        const int n = q / 12, kb = q - n * 12;
        f16x8 v;
        #pragma unroll
        for (int d = 0; d < 8; ++d) {
            const int kk = kb * 8 + d;
            v[d] = (_Float16)((n < N2 && kk < N1) ? nw2[kk * N2 + n] : 0.f);
        }
        *(f16x8*)&nw2T[n * 96 + kb * 8] = v;
    }
}

// ---------------------------------------------------------------------------
// fused kernel: grid = 1024 (block = (b, half)), 512 threads (8 waves).
// Block owns i-rows [16*half, 16*half+16); j runs over all 32 rows.
// Phases: B1(stage) -> {enL1(w0-5) + eeRnd0(all)} -> B2 ->
//         {enL2(w0-1) + eeRnd1(all)} -> B3 -> enL3(t<128) -> B4 -> combine.
// ---------------------------------------------------------------------------
__global__ __launch_bounds__(512, 6) void k_fused(
    const float* __restrict__ rs, const float* __restrict__ xs,
    const float* __restrict__ coords,
    const float* __restrict__ eb1, const float* __restrict__ ew2,
    const float* __restrict__ eb2, const float* __restrict__ ew3,
    const float* __restrict__ eb3, const float* __restrict__ nb1,
    const float* __restrict__ nb2, const float* __restrict__ nb3,
    const float* __restrict__ nw3, const _Float16* __restrict__ wsp,
    float* __restrict__ out)
{
    __shared__ alignas(16) _Float16 xs_h[N_ * 256];     // 16384 B, swizzled
    __shared__ alignas(16) _Float16 ew1T_s[48 * 256];   // 24576 B, swizzled
    __shared__ alignas(16) _Float16 h1e[16 * HEP];      //  3072 B
    __shared__ alignas(16) float    h2e[16 * 26];       //  1664 B
    __shared__ alignas(16) float    eb1_s[48];          // eb1*log2e, padded
    __shared__ alignas(16) float    b2_s[16];           // eb2*log2e, padded
    __shared__ float rs_s[96], nw3_s[200], nb2_s[32], nb3_s[8], co_s[24];
    __shared__ float bfn_s[48], cut_s[16], bfe_s[48];

    const int bid = blockIdx.x;
    const int b = bid >> 1, rbase = (bid & 1) << 4;     // this block's i-rows
    const int t = threadIdx.x;
    const int wv = t >> 6, l = t & 63, quad = l >> 4, c = l & 15;

    const _Float16* ew1T_g = wsp;
    const _Float16* nw1T_g = wsp + 48 * 256;
    const _Float16* nw2T_g = wsp + 48 * 256 + 96 * 256;

    // ---- issue ew1T DMA: 24576 B = 3 rounds x (512 lanes x 16 B) ----
    {
        const char* g = (const char*)ew1T_g;
        char* d = (char*)ew1T_s;
        const int wb = wv * 1024;
        #pragma unroll
        for (int r = 0; r < 3; ++r)
            lds_dma16(d + r * 8192 + wb, g + r * 8192 + wb + (l << 4));
    }
    // ---- stage xs[b] fp32 -> swizzled f16 (2 x 16B blocks per thread) ----
    {
        const float4* src = (const float4*)(xs + (size_t)b * N_ * D_);
        #pragma unroll
        for (int u = 0; u < 2; ++u) {
            const int idx = t + 512 * u;                // 1024 = 32 rows x 32 kb
            const int row = idx >> 5, kb = idx & 31;
            float4 v0 = src[idx << 1];
            float4 v1 = src[(idx << 1) + 1];
            union { _Float16 h[8]; uint4 q; } pk;
            pk.h[0] = (_Float16)v0.x; pk.h[1] = (_Float16)v0.y;
            pk.h[2] = (_Float16)v0.z; pk.h[3] = (_Float16)v0.w;
            pk.h[4] = (_Float16)v1.x; pk.h[5] = (_Float16)v1.y;
            pk.h[6] = (_Float16)v1.z; pk.h[7] = (_Float16)v1.w;
            *(uint4*)&xs_h[row * 256 + ((kb ^ (row & 7)) << 3)] = pk.q;
        }
    }
    // ---- misc small stages ----
    if (t < 96)  rs_s[t] = rs[b * 96 + t];
    if (t < 200) nw3_s[t] = nw3[t] * LN2f;
    if (t < N2)  nb2_s[t] = nb2[t] * L2Ef;
    if (t < N3)  nb3_s[t] = nb3[t];
    if (t < 24)  co_s[t] = coords[t];
    if (t < 48)  eb1_s[t] = (t < E1) ? eb1[t] * L2Ef : 0.f;
    if (t < 16)  b2_s[t] = (t < E2) ? eb2[t] * L2Ef : 0.f;
    if (t < 384) ((uint64_t*)h1e)[t] = 0ull;            // zero k-pad cols 81..95

    // ---- per-lane register constants (global reads, independent of LDS) ----
    f16x4 b2fT[3];
    #pragma unroll
    for (int Nt = 0; Nt < 3; ++Nt) {
        f16x4 p;
        #pragma unroll
        for (int r = 0; r < 4; ++r) {
            const int n = Nt * 16 + quad * 4 + r;
            p[r] = (_Float16)((n < E1 && c < E2) ? ew2[n * E2 + c] : 0.f);
        }
        b2fT[Nt] = p;
    }
    float w3q[4];
    #pragma unroll
    for (int r = 0; r < 4; ++r) {
        const int m = quad * 4 + r;
        w3q[r] = (m < E2) ? ew3[m] * LN2f : 0.f;
    }
    const float eb3v = eb3[0];

    __syncthreads();   // B1: xs_h + ew1T_s (DMA drained) + misc ready

    // ---- ee round: one i-row per wave per round --------------------------
    auto ee_round = [&](int lr) {
        const int i = rbase + lr;
        f32x4 acc[2][3];
        #pragma unroll
        for (int Nt = 0; Nt < 3; ++Nt) {
            f32x4 bias = *(const f32x4*)&eb1_s[Nt * 16 + quad * 4];
            acc[0][Nt] = bias;
            acc[1][Nt] = bias;
        }
        #pragma unroll
        for (int Kt = 0; Kt < 8; ++Kt) {
            const int kb = Kt * 4 + quad;
            const int sj = (kb ^ (c & 7)) << 3;
            f16x8 iv  = *(const f16x8*)&xs_h[i * 256 + ((kb ^ (i & 7)) << 3)];
            f16x8 jv0 = *(const f16x8*)&xs_h[c * 256 + sj];
            f16x8 jv1 = *(const f16x8*)&xs_h[(16 + c) * 256 + sj];
            f16x8 P0 = iv * jv0;               // B-operand: B[k][j=c]
            f16x8 P1 = iv * jv1;
            #pragma unroll
            for (int Nt = 0; Nt < 3; ++Nt) {
                f16x8 b1 = *(const f16x8*)&ew1T_s[(Nt * 16 + c) * 256 + sj];
                acc[0][Nt] = MFMA32(b1, P0, acc[0][Nt]);
                acc[1][Nt] = MFMA32(b1, P1, acc[1][Nt]);
            }
        }
        const float rix = rs_s[i * 3 + 0], riy = rs_s[i * 3 + 1], riz = rs_s[i * 3 + 2];
        float cxi = 0.f, cyi = 0.f, czi = 0.f;
        const f32x4 b2i = *(const f32x4*)&b2_s[quad * 4];
        #pragma unroll
        for (int h = 0; h < 2; ++h) {
            f32x4 acc2 = b2i;
            #pragma unroll
            for (int Nt = 0; Nt < 3; ++Nt) {
                f16x4 bh_;
                #pragma unroll
                for (int r2 = 0; r2 < 4; ++r2)
                    bh_[r2] = (_Float16)ssp2(acc[h][Nt][r2]);
                acc2 = MFMA16(b2fT[Nt], bh_, acc2);
            }
            float wsum = 0.f;
            #pragma unroll
            for (int r2 = 0; r2 < 4; ++r2)
                wsum = fmaf(w3q[r2], ssp2(acc2[r2]), wsum);
            wsum += __shfl_xor(wsum, 16);
            wsum += __shfl_xor(wsum, 32);      // allreduce over quads (m)
            const float wj = wsum + eb3v;
            const int j = c + 16 * h;
            cxi = fmaf(wj, rix - rs_s[j * 3 + 0], cxi);
            cyi = fmaf(wj, riy - rs_s[j * 3 + 1], cyi);
            czi = fmaf(wj, riz - rs_s[j * 3 + 2], czi);
        }
        #pragma unroll
        for (int m2 = 1; m2 < 16; m2 <<= 1) {
            cxi += __shfl_xor(cxi, m2);
            cyi += __shfl_xor(cyi, m2);
            czi += __shfl_xor(czi, m2);
        }
        if (l == 0) {
            bfe_s[lr * 3 + 0] = cxi;
            bfe_s[lr * 3 + 1] = cyi;
            bfe_s[lr * 3 + 2] = czi;
        }
    };

    // ---- phase A: en L1 (waves 0-5, B direct from L2) + ee round 0 -------
    if (wv < 6) {
        const int n_col = wv * 16 + c;                  // neuron (0..95)
        const float nb1v = (n_col < N1) ? nb1[n_col] * L2Ef : 0.f;
        const _Float16* bg = nw1T_g + n_col * 256 + quad * 8;
        f32x4 acc1 = (f32x4){0.f, 0.f, 0.f, 0.f};
        f16x8 Bp = *(const f16x8*)bg;
        #pragma unroll
        for (int Kt = 0; Kt < 8; ++Kt) {
            f16x8 Bf = Bp;
            if (Kt < 7) Bp = *(const f16x8*)(bg + (Kt + 1) * 32);
            f16x8 A = *(const f16x8*)&xs_h[(rbase + c) * 256 +
                                           (((Kt * 4 + quad) ^ (c & 7)) << 3)];
            acc1 = MFMA32(A, Bf, acc1);
        }
        if (n_col < N1) {
            #pragma unroll
            for (int r2 = 0; r2 < 4; ++r2)
                h1e[(quad * 4 + r2) * HEP + n_col] = (_Float16)ssp2(acc1[r2] + nb1v);
        }
    }
    ee_round(wv);
    __syncthreads();   // B2: h1e done, ee round 0 done

    // ---- phase B: en L2 (waves 0-1, B direct from L2) + ee round 1 -------
    if (wv < 2) {
        const int n = wv * 16 + c;                      // 0..31
        const _Float16* bg2 = nw2T_g + n * 96 + quad * 8;
        f32x4 acc2 = (f32x4){0.f, 0.f, 0.f, 0.f};
        #pragma unroll
        for (int Kt2 = 0; Kt2 < 3; ++Kt2) {
            f16x8 A  = *(const f16x8*)&h1e[c * HEP + Kt2 * 32 + quad * 8];
            f16x8 Bf = *(const f16x8*)(bg2 + Kt2 * 32);
            acc2 = MFMA32(A, Bf, acc2);
        }
        if (n < N2) {
            #pragma unroll
            for (int r2 = 0; r2 < 4; ++r2)
                h2e[(quad * 4 + r2) * 26 + n] = ssp2(acc2[r2] + nb2_s[n]);
        }
    }
    ee_round(wv + 8);
    __syncthreads();   // B3: h2e ready, ee round 1 done

    // ---- phase C: en L3 + bf_nuc + cutoff (threads 0..127) ---------------
    if (t < 128) {
        const int r = t >> 3, s = t & 7;
        const int gi = rbase + r;
        float w = nb3_s[s];
        const int rb26 = r * 26;
        #pragma unroll
        for (int kk = 0; kk < N2; ++kk)
            w = fmaf(h2e[rb26 + kk], nw3_s[kk * N3 + s], w);
        const float dx = rs_s[gi * 3 + 0] - co_s[s * 3 + 0];
        const float dy = rs_s[gi * 3 + 1] - co_s[s * 3 + 1];
        const float dz = rs_s[gi * 3 + 2] - co_s[s * 3 + 2];
        float cx = w * dx, cy = w * dy, cz = w * dz;
        #pragma unroll
        for (int m2 = 1; m2 < 8; m2 <<= 1) {
            cx += __shfl_xor(cx, m2);
            cy += __shfl_xor(cy, m2);
            cz += __shfl_xor(cz, m2);
        }
        const float rr  = sqrtf(dx * dx + dy * dy + dz * dz);
        const float xsc = 2.f * rr;            // r / L, L = 0.5
        float cf = (xsc < 0.5f) ? xsc * xsc * (6.f - 8.f * xsc + 3.f * xsc * xsc) : 1.f;
        #pragma unroll
        for (int m2 = 1; m2 < 8; m2 <<= 1) cf *= __shfl_xor(cf, m2);
        if (s == 0) {
            bfn_s[r * 3 + 0] = cx;
            bfn_s[r * 3 + 1] = cy;
            bfn_s[r * 3 + 2] = cz;
            cut_s[r] = cf;
        }
    }
    __syncthreads();   // B4: bfn_s/cut_s ready

    // ---- final combine + store (threads 0..47: this block's 16 rows) -----
    if (t < 48) {
        const int r = t / 3;
        out[(size_t)b * (N_ * 3) + rbase * 3 + t] =
            rs_s[rbase * 3 + t] + 1e-4f * cut_s[r] * (bfe_s[t] + bfn_s[t]);
    }
}

extern "C" void kernel_launch(void* const* d_in, const int* in_sizes, int n_in,
                              void* d_out, int out_size, void* d_ws, size_t ws_size,
                              hipStream_t stream)
{
    const float* rs     = (const float*)d_in[0];
    const float* xs     = (const float*)d_in[1];
    const float* coords = (const float*)d_in[2];
    const float* ew1    = (const float*)d_in[3];
    const float* eb1    = (const float*)d_in[4];
    const float* ew2    = (const float*)d_in[5];
    const float* eb2    = (const float*)d_in[6];
    const float* ew3    = (const float*)d_in[7];
    const float* eb3    = (const float*)d_in[8];
    const float* nw1    = (const float*)d_in[9];
    const float* nb1    = (const float*)d_in[10];
    const float* nw2    = (const float*)d_in[11];
    const float* nb2    = (const float*)d_in[12];
    const float* nw3    = (const float*)d_in[13];
    const float* nb3    = (const float*)d_in[14];

    _Float16* wsp = (_Float16*)d_ws;   // 79,872 B used

    k_prep<<<20, 256, 0, stream>>>(ew1, nw1, nw2, wsp);
    k_fused<<<B_ * 2, 512, 0, stream>>>(rs, xs, coords, eb1, ew2, eb2, ew3, eb3,
                                        nb1, nb2, nb3, nw3, wsp, (float*)d_out);
}

// Round 3
// 128.398 us; speedup vs baseline: 1.0209x; 1.0209x over previous
//
#include <hip/hip_runtime.h>
#include <stdint.h>

// ---------------------------------------------------------------------------
// R11 restructure: occupancy + de-staging.
//  - grid 1024 (2 blocks per batch elem, 16 i-rows each), 512 thr.
//  - k_prep pre-transposes ew1/nw1/nw2 to f16 in d_ws (pre-scaled by log2e);
//    per-block transpose dances deleted. en L1/L2 B-frags read direct from L2.
//  - W1^T (ee) lives in LDS (DMA'd via global_load_lds), not 96 VGPRs.
//  - xs_h / ew1T LDS: unpadded [row][256] f16 with 16B-block XOR swizzle
//    (kb ^= row&7) applied at producer AND consumer.
// R12: fix MFMA16 builtin spelling via __has_builtin guard.
// R13: launch_bounds second arg is empirically CUDA-style minBlocksPerCU on
//    this toolchain (arg=6 -> VGPR cap 40 -> 30 MB scratch spills/dispatch).
//    Pin (512, 3): 3 blocks/CU x 8 waves = 24 waves/CU, VGPR cap ~84.
// ---------------------------------------------------------------------------

static constexpr int B_ = 512, N_ = 32, D_ = 256, K_ = 8;
static constexpr int E1 = 40, E2 = 6;          // ee MLP 256->40->6->1
static constexpr int N1 = 81, N2 = 25, N3 = 8; // en MLP 256->81->25->8
static constexpr int HEP = 96;                 // h1e row stride (f16)
static constexpr float LN2f = 0.69314718055994530942f;
static constexpr float L2Ef = 1.44269504088896340736f;

typedef float    f32x4 __attribute__((ext_vector_type(4)));
typedef _Float16 f16x8 __attribute__((ext_vector_type(8)));
typedef _Float16 f16x4 __attribute__((ext_vector_type(4)));

#define MFMA32(A, B, C) __builtin_amdgcn_mfma_f32_16x16x32_f16((A), (B), (C), 0, 0, 0)
#if __has_builtin(__builtin_amdgcn_mfma_f32_16x16x16_f16)
#define MFMA16(A, B, C) __builtin_amdgcn_mfma_f32_16x16x16_f16((A), (B), (C), 0, 0, 0)
#else
#define MFMA16(A, B, C) __builtin_amdgcn_mfma_f32_16x16x16f16((A), (B), (C), 0, 0, 0)
#endif

// base-2 shifted softplus: ssp(x)/ln2 with t = x*log2e (v_log_f32 is log2).
__device__ __forceinline__ float ssp2(float t) {
    float e = __builtin_amdgcn_exp2f(t);
    return __builtin_amdgcn_logf(fmaf(e, 0.5f, 0.5f));
}

__device__ __forceinline__ void lds_dma16(void* lds, const void* g) {
    __builtin_amdgcn_global_load_lds(
        (const __attribute__((address_space(1))) unsigned int*)(uintptr_t)g,
        (__attribute__((address_space(3))) unsigned int*)(uintptr_t)lds,
        16, 0, 0);
}

// ---------------------------------------------------------------------------
// prep kernel: weights -> f16 transposed layouts in workspace (once/launch).
//   ew1T [48][256] f16, *log2e, 16B-block XOR-swizzled (consumed from LDS)
//   nw1T [96][256] f16, *log2e, plain           (consumed from global/L2)
//   nw2T [32][ 96] f16, raw,    plain           (consumed from global/L2)
// ---------------------------------------------------------------------------
__global__ __launch_bounds__(256) void k_prep(
    const float* __restrict__ ew1, const float* __restrict__ nw1,
    const float* __restrict__ nw2, _Float16* __restrict__ wsp)
{
    const int g = blockIdx.x * 256 + threadIdx.x;
    _Float16* ew1T = wsp;
    _Float16* nw1T = wsp + 48 * 256;
    _Float16* nw2T = wsp + 48 * 256 + 96 * 256;

    if (g < 1536) {                         // ew1T: 48 rows x 32 kb
        const int n = g >> 5, kb = g & 31;
        f16x8 v;
        #pragma unroll
        for (int d = 0; d < 8; ++d) {
            const int k = kb * 8 + d;
            v[d] = (_Float16)((n < E1) ? ew1[k * E1 + n] * L2Ef : 0.f);
        }
        *(f16x8*)&ew1T[n * 256 + ((kb ^ (n & 7)) << 3)] = v;
    } else if (g < 4608) {                  // nw1T: 96 rows x 32 kb
        const int q = g - 1536;
        const int n = q >> 5, kb = q & 31;
        f16x8 v;
        #pragma unroll
        for (int d = 0; d < 8; ++d) {
            const int k = kb * 8 + d;
            v[d] = (_Float16)((n < N1) ? nw1[k * N1 + n] * L2Ef : 0.f);
        }
        *(f16x8*)&nw1T[n * 256 + kb * 8] = v;
    } else if (g < 4992) {                  // nw2T: 32 rows x 12 kb (96 k)
        const int q = g - 4608;
        const int n = q / 12, kb = q - n * 12;
        f16x8 v;
        #pragma unroll
        for (int d = 0; d < 8; ++d) {
            const int kk = kb * 8 + d;
            v[d] = (_Float16)((n < N2 && kk < N1) ? nw2[kk * N2 + n] : 0.f);
        }
        *(f16x8*)&nw2T[n * 96 + kb * 8] = v;
    }
}

// ---------------------------------------------------------------------------
// fused kernel: grid = 1024 (block = (b, half)), 512 threads (8 waves).
// Block owns i-rows [16*half, 16*half+16); j runs over all 32 rows.
// Phases: B1(stage) -> {enL1(w0-5) + eeRnd0(all)} -> B2 ->
//         {enL2(w0-1) + eeRnd1(all)} -> B3 -> enL3(t<128) -> B4 -> combine.
// ---------------------------------------------------------------------------
__global__ __launch_bounds__(512, 3) void k_fused(
    const float* __restrict__ rs, const float* __restrict__ xs,
    const float* __restrict__ coords,
    const float* __restrict__ eb1, const float* __restrict__ ew2,
    const float* __restrict__ eb2, const float* __restrict__ ew3,
    const float* __restrict__ eb3, const float* __restrict__ nb1,
    const float* __restrict__ nb2, const float* __restrict__ nb3,
    const float* __restrict__ nw3, const _Float16* __restrict__ wsp,
    float* __restrict__ out)
{
    __shared__ alignas(16) _Float16 xs_h[N_ * 256];     // 16384 B, swizzled
    __shared__ alignas(16) _Float16 ew1T_s[48 * 256];   // 24576 B, swizzled
    __shared__ alignas(16) _Float16 h1e[16 * HEP];      //  3072 B
    __shared__ alignas(16) float    h2e[16 * 26];       //  1664 B
    __shared__ alignas(16) float    eb1_s[48];          // eb1*log2e, padded
    __shared__ alignas(16) float    b2_s[16];           // eb2*log2e, padded
    __shared__ float rs_s[96], nw3_s[200], nb2_s[32], nb3_s[8], co_s[24];
    __shared__ float bfn_s[48], cut_s[16], bfe_s[48];

    const int bid = blockIdx.x;
    const int b = bid >> 1, rbase = (bid & 1) << 4;     // this block's i-rows
    const int t = threadIdx.x;
    const int wv = t >> 6, l = t & 63, quad = l >> 4, c = l & 15;

    const _Float16* ew1T_g = wsp;
    const _Float16* nw1T_g = wsp + 48 * 256;
    const _Float16* nw2T_g = wsp + 48 * 256 + 96 * 256;

    // ---- issue ew1T DMA: 24576 B = 3 rounds x (512 lanes x 16 B) ----
    {
        const char* g = (const char*)ew1T_g;
        char* d = (char*)ew1T_s;
        const int wb = wv * 1024;
        #pragma unroll
        for (int r = 0; r < 3; ++r)
            lds_dma16(d + r * 8192 + wb, g + r * 8192 + wb + (l << 4));
    }
    // ---- stage xs[b] fp32 -> swizzled f16 (2 x 16B blocks per thread) ----
    {
        const float4* src = (const float4*)(xs + (size_t)b * N_ * D_);
        #pragma unroll
        for (int u = 0; u < 2; ++u) {
            const int idx = t + 512 * u;                // 1024 = 32 rows x 32 kb
            const int row = idx >> 5, kb = idx & 31;
            float4 v0 = src[idx << 1];
            float4 v1 = src[(idx << 1) + 1];
            union { _Float16 h[8]; uint4 q; } pk;
            pk.h[0] = (_Float16)v0.x; pk.h[1] = (_Float16)v0.y;
            pk.h[2] = (_Float16)v0.z; pk.h[3] = (_Float16)v0.w;
            pk.h[4] = (_Float16)v1.x; pk.h[5] = (_Float16)v1.y;
            pk.h[6] = (_Float16)v1.z; pk.h[7] = (_Float16)v1.w;
            *(uint4*)&xs_h[row * 256 + ((kb ^ (row & 7)) << 3)] = pk.q;
        }
    }
    // ---- misc small stages ----
    if (t < 96)  rs_s[t] = rs[b * 96 + t];
    if (t < 200) nw3_s[t] = nw3[t] * LN2f;
    if (t < N2)  nb2_s[t] = nb2[t] * L2Ef;
    if (t < N3)  nb3_s[t] = nb3[t];
    if (t < 24)  co_s[t] = coords[t];
    if (t < 48)  eb1_s[t] = (t < E1) ? eb1[t] * L2Ef : 0.f;
    if (t < 16)  b2_s[t] = (t < E2) ? eb2[t] * L2Ef : 0.f;
    if (t < 384) ((uint64_t*)h1e)[t] = 0ull;            // zero k-pad cols 81..95

    // ---- per-lane register constants (global reads, independent of LDS) ----
    f16x4 b2fT[3];
    #pragma unroll
    for (int Nt = 0; Nt < 3; ++Nt) {
        f16x4 p;
        #pragma unroll
        for (int r = 0; r < 4; ++r) {
            const int n = Nt * 16 + quad * 4 + r;
            p[r] = (_Float16)((n < E1 && c < E2) ? ew2[n * E2 + c] : 0.f);
        }
        b2fT[Nt] = p;
    }
    float w3q[4];
    #pragma unroll
    for (int r = 0; r < 4; ++r) {
        const int m = quad * 4 + r;
        w3q[r] = (m < E2) ? ew3[m] * LN2f : 0.f;
    }
    const float eb3v = eb3[0];

    __syncthreads();   // B1: xs_h + ew1T_s (DMA drained) + misc ready

    // ---- ee round: one i-row per wave per round --------------------------
    auto ee_round = [&](int lr) {
        const int i = rbase + lr;
        f32x4 acc[2][3];
        #pragma unroll
        for (int Nt = 0; Nt < 3; ++Nt) {
            f32x4 bias = *(const f32x4*)&eb1_s[Nt * 16 + quad * 4];
            acc[0][Nt] = bias;
            acc[1][Nt] = bias;
        }
        #pragma unroll
        for (int Kt = 0; Kt < 8; ++Kt) {
            const int kb = Kt * 4 + quad;
            const int sj = (kb ^ (c & 7)) << 3;
            f16x8 iv  = *(const f16x8*)&xs_h[i * 256 + ((kb ^ (i & 7)) << 3)];
            f16x8 jv0 = *(const f16x8*)&xs_h[c * 256 + sj];
            f16x8 jv1 = *(const f16x8*)&xs_h[(16 + c) * 256 + sj];
            f16x8 P0 = iv * jv0;               // B-operand: B[k][j=c]
            f16x8 P1 = iv * jv1;
            #pragma unroll
            for (int Nt = 0; Nt < 3; ++Nt) {
                f16x8 b1 = *(const f16x8*)&ew1T_s[(Nt * 16 + c) * 256 + sj];
                acc[0][Nt] = MFMA32(b1, P0, acc[0][Nt]);
                acc[1][Nt] = MFMA32(b1, P1, acc[1][Nt]);
            }
        }
        const float rix = rs_s[i * 3 + 0], riy = rs_s[i * 3 + 1], riz = rs_s[i * 3 + 2];
        float cxi = 0.f, cyi = 0.f, czi = 0.f;
        const f32x4 b2i = *(const f32x4*)&b2_s[quad * 4];
        #pragma unroll
        for (int h = 0; h < 2; ++h) {
            f32x4 acc2 = b2i;
            #pragma unroll
            for (int Nt = 0; Nt < 3; ++Nt) {
                f16x4 bh_;
                #pragma unroll
                for (int r2 = 0; r2 < 4; ++r2)
                    bh_[r2] = (_Float16)ssp2(acc[h][Nt][r2]);
                acc2 = MFMA16(b2fT[Nt], bh_, acc2);
            }
            float wsum = 0.f;
            #pragma unroll
            for (int r2 = 0; r2 < 4; ++r2)
                wsum = fmaf(w3q[r2], ssp2(acc2[r2]), wsum);
            wsum += __shfl_xor(wsum, 16);
            wsum += __shfl_xor(wsum, 32);      // allreduce over quads (m)
            const float wj = wsum + eb3v;
            const int j = c + 16 * h;
            cxi = fmaf(wj, rix - rs_s[j * 3 + 0], cxi);
            cyi = fmaf(wj, riy - rs_s[j * 3 + 1], cyi);
            czi = fmaf(wj, riz - rs_s[j * 3 + 2], czi);
        }
        #pragma unroll
        for (int m2 = 1; m2 < 16; m2 <<= 1) {
            cxi += __shfl_xor(cxi, m2);
            cyi += __shfl_xor(cyi, m2);
            czi += __shfl_xor(czi, m2);
        }
        if (l == 0) {
            bfe_s[lr * 3 + 0] = cxi;
            bfe_s[lr * 3 + 1] = cyi;
            bfe_s[lr * 3 + 2] = czi;
        }
    };

    // ---- phase A: en L1 (waves 0-5, B direct from L2) + ee round 0 -------
    if (wv < 6) {
        const int n_col = wv * 16 + c;                  // neuron (0..95)
        const float nb1v = (n_col < N1) ? nb1[n_col] * L2Ef : 0.f;
        const _Float16* bg = nw1T_g + n_col * 256 + quad * 8;
        f32x4 acc1 = (f32x4){0.f, 0.f, 0.f, 0.f};
        f16x8 Bp = *(const f16x8*)bg;
        #pragma unroll
        for (int Kt = 0; Kt < 8; ++Kt) {
            f16x8 Bf = Bp;
            if (Kt < 7) Bp = *(const f16x8*)(bg + (Kt + 1) * 32);
            f16x8 A = *(const f16x8*)&xs_h[(rbase + c) * 256 +
                                           (((Kt * 4 + quad) ^ (c & 7)) << 3)];
            acc1 = MFMA32(A, Bf, acc1);
        }
        if (n_col < N1) {
            #pragma unroll
            for (int r2 = 0; r2 < 4; ++r2)
                h1e[(quad * 4 + r2) * HEP + n_col] = (_Float16)ssp2(acc1[r2] + nb1v);
        }
    }
    ee_round(wv);
    __syncthreads();   // B2: h1e done, ee round 0 done

    // ---- phase B: en L2 (waves 0-1, B direct from L2) + ee round 1 -------
    if (wv < 2) {
        const int n = wv * 16 + c;                      // 0..31
        const _Float16* bg2 = nw2T_g + n * 96 + quad * 8;
        f32x4 acc2 = (f32x4){0.f, 0.f, 0.f, 0.f};
        #pragma unroll
        for (int Kt2 = 0; Kt2 < 3; ++Kt2) {
            f16x8 A  = *(const f16x8*)&h1e[c * HEP + Kt2 * 32 + quad * 8];
            f16x8 Bf = *(const f16x8*)(bg2 + Kt2 * 32);
            acc2 = MFMA32(A, Bf, acc2);
        }
        if (n < N2) {
            #pragma unroll
            for (int r2 = 0; r2 < 4; ++r2)
                h2e[(quad * 4 + r2) * 26 + n] = ssp2(acc2[r2] + nb2_s[n]);
        }
    }
    ee_round(wv + 8);
    __syncthreads();   // B3: h2e ready, ee round 1 done

    // ---- phase C: en L3 + bf_nuc + cutoff (threads 0..127) ---------------
    if (t < 128) {
        const int r = t >> 3, s = t & 7;
        const int gi = rbase + r;
        float w = nb3_s[s];
        const int rb26 = r * 26;
        #pragma unroll
        for (int kk = 0; kk < N2; ++kk)
            w = fmaf(h2e[rb26 + kk], nw3_s[kk * N3 + s], w);
        const float dx = rs_s[gi * 3 + 0] - co_s[s * 3 + 0];
        const float dy = rs_s[gi * 3 + 1] - co_s[s * 3 + 1];
        const float dz = rs_s[gi * 3 + 2] - co_s[s * 3 + 2];
        float cx = w * dx, cy = w * dy, cz = w * dz;
        #pragma unroll
        for (int m2 = 1; m2 < 8; m2 <<= 1) {
            cx += __shfl_xor(cx, m2);
            cy += __shfl_xor(cy, m2);
            cz += __shfl_xor(cz, m2);
        }
        const float rr  = sqrtf(dx * dx + dy * dy + dz * dz);
        const float xsc = 2.f * rr;            // r / L, L = 0.5
        float cf = (xsc < 0.5f) ? xsc * xsc * (6.f - 8.f * xsc + 3.f * xsc * xsc) : 1.f;
        #pragma unroll
        for (int m2 = 1; m2 < 8; m2 <<= 1) cf *= __shfl_xor(cf, m2);
        if (s == 0) {
            bfn_s[r * 3 + 0] = cx;
            bfn_s[r * 3 + 1] = cy;
            bfn_s[r * 3 + 2] = cz;
            cut_s[r] = cf;
        }
    }
    __syncthreads();   // B4: bfn_s/cut_s ready

    // ---- final combine + store (threads 0..47: this block's 16 rows) -----
    if (t < 48) {
        const int r = t / 3;
        out[(size_t)b * (N_ * 3) + rbase * 3 + t] =
            rs_s[rbase * 3 + t] + 1e-4f * cut_s[r] * (bfe_s[t] + bfn_s[t]);
    }
}

extern "C" void kernel_launch(void* const* d_in, const int* in_sizes, int n_in,
                              void* d_out, int out_size, void* d_ws, size_t ws_size,
                              hipStream_t stream)
{
    const float* rs     = (const float*)d_in[0];
    const float* xs     = (const float*)d_in[1];
    const float* coords = (const float*)d_in[2];
    const float* ew1    = (const float*)d_in[3];
    const float* eb1    = (const float*)d_in[4];
    const float* ew2    = (const float*)d_in[5];
    const float* eb2    = (const float*)d_in[6];
    const float* ew3    = (const float*)d_in[7];
    const float* eb3    = (const float*)d_in[8];
    const float* nw1    = (const float*)d_in[9];
    const float* nb1    = (const float*)d_in[10];
    const float* nw2    = (const float*)d_in[11];
    const float* nb2    = (const float*)d_in[12];
    const float* nw3    = (const float*)d_in[13];
    const float* nb3    = (const float*)d_in[14];

    _Float16* wsp = (_Float16*)d_ws;   // 79,872 B used

    k_prep<<<20, 256, 0, stream>>>(ew1, nw1, nw2, wsp);
    k_fused<<<B_ * 2, 512, 0, stream>>>(rs, xs, coords, eb1, ew2, eb2, ew3, eb3,
                                        nb1, nb2, nb3, nw3, wsp, (float*)d_out);
}

// Round 4
// 124.474 us; speedup vs baseline: 1.0531x; 1.0315x over previous
//
#include <hip/hip_runtime.h>
#include <stdint.h>

// ---------------------------------------------------------------------------
// R11 restructure: occupancy + de-staging (k_prep pre-transposes weights to
//   f16 in d_ws; grid 1024 = 2 blocks/batch-elem; W1^T in LDS via DMA;
//   xs_h/ew1T unpadded [row][256] f16 with 16B-block XOR swizzle).
// R12: MFMA16 builtin spelling guard.
// R13: launch_bounds 2nd arg is CUDA-style minBlocksPerCU here; (512,3) gave
//   VGPR=52, no spills, occupancy 30% -- and time UNCHANGED (~47us). Occupancy
//   is not the limiter.
// R14: LDS-pipe is the most-loaded resource (~55% busy: 768 b128 ee reads +
//   staging + shfl per block). Fuse the two ee rounds: both i-rows (wv, wv+8)
//   in one K-loop -> 7 b128 per K-step for 12 MFMA (was 12 b128). ee reads
//   768->448 per block. acc doubles to 48 VGPRs -> pin (512,2) (cap 128,
//   2 blocks/CU, no spill). Bank-conflict counter is layout-invariant (shfl
//   inherent) -- not chased.
// ---------------------------------------------------------------------------

static constexpr int B_ = 512, N_ = 32, D_ = 256, K_ = 8;
static constexpr int E1 = 40, E2 = 6;          // ee MLP 256->40->6->1
static constexpr int N1 = 81, N2 = 25, N3 = 8; // en MLP 256->81->25->8
static constexpr int HEP = 96;                 // h1e row stride (f16)
static constexpr float LN2f = 0.69314718055994530942f;
static constexpr float L2Ef = 1.44269504088896340736f;

typedef float    f32x4 __attribute__((ext_vector_type(4)));
typedef _Float16 f16x8 __attribute__((ext_vector_type(8)));
typedef _Float16 f16x4 __attribute__((ext_vector_type(4)));

#define MFMA32(A, B, C) __builtin_amdgcn_mfma_f32_16x16x32_f16((A), (B), (C), 0, 0, 0)
#if __has_builtin(__builtin_amdgcn_mfma_f32_16x16x16_f16)
#define MFMA16(A, B, C) __builtin_amdgcn_mfma_f32_16x16x16_f16((A), (B), (C), 0, 0, 0)
#else
#define MFMA16(A, B, C) __builtin_amdgcn_mfma_f32_16x16x16f16((A), (B), (C), 0, 0, 0)
#endif

// base-2 shifted softplus: ssp(x)/ln2 with t = x*log2e (v_log_f32 is log2).
__device__ __forceinline__ float ssp2(float t) {
    float e = __builtin_amdgcn_exp2f(t);
    return __builtin_amdgcn_logf(fmaf(e, 0.5f, 0.5f));
}

__device__ __forceinline__ void lds_dma16(void* lds, const void* g) {
    __builtin_amdgcn_global_load_lds(
        (const __attribute__((address_space(1))) unsigned int*)(uintptr_t)g,
        (__attribute__((address_space(3))) unsigned int*)(uintptr_t)lds,
        16, 0, 0);
}

// ---------------------------------------------------------------------------
// prep kernel: weights -> f16 transposed layouts in workspace (once/launch).
//   ew1T [48][256] f16, *log2e, 16B-block XOR-swizzled (consumed from LDS)
//   nw1T [96][256] f16, *log2e, plain           (consumed from global/L2)
//   nw2T [32][ 96] f16, raw,    plain           (consumed from global/L2)
// ---------------------------------------------------------------------------
__global__ __launch_bounds__(256) void k_prep(
    const float* __restrict__ ew1, const float* __restrict__ nw1,
    const float* __restrict__ nw2, _Float16* __restrict__ wsp)
{
    const int g = blockIdx.x * 256 + threadIdx.x;
    _Float16* ew1T = wsp;
    _Float16* nw1T = wsp + 48 * 256;
    _Float16* nw2T = wsp + 48 * 256 + 96 * 256;

    if (g < 1536) {                         // ew1T: 48 rows x 32 kb
        const int n = g >> 5, kb = g & 31;
        f16x8 v;
        #pragma unroll
        for (int d = 0; d < 8; ++d) {
            const int k = kb * 8 + d;
            v[d] = (_Float16)((n < E1) ? ew1[k * E1 + n] * L2Ef : 0.f);
        }
        *(f16x8*)&ew1T[n * 256 + ((kb ^ (n & 7)) << 3)] = v;
    } else if (g < 4608) {                  // nw1T: 96 rows x 32 kb
        const int q = g - 1536;
        const int n = q >> 5, kb = q & 31;
        f16x8 v;
        #pragma unroll
        for (int d = 0; d < 8; ++d) {
            const int k = kb * 8 + d;
            v[d] = (_Float16)((n < N1) ? nw1[k * N1 + n] * L2Ef : 0.f);
        }
        *(f16x8*)&nw1T[n * 256 + kb * 8] = v;
    } else if (g < 4992) {                  // nw2T: 32 rows x 12 kb (96 k)
        const int q = g - 4608;
        const int n = q / 12, kb = q - n * 12;
        f16x8 v;
        #pragma unroll
        for (int d = 0; d < 8; ++d) {
            const int kk = kb * 8 + d;
            v[d] = (_Float16)((n < N2 && kk < N1) ? nw2[kk * N2 + n] : 0.f);
        }
        *(f16x8*)&nw2T[n * 96 + kb * 8] = v;
    }
}

// ---------------------------------------------------------------------------
// fused kernel: grid = 1024 (block = (b, half)), 512 threads (8 waves).
// Block owns i-rows [16*half, 16*half+16); j runs over all 32 rows.
// Phases: B1(stage) -> {enL1(w0-5); fused ee both rows (all waves)} -> B2 ->
//         enL2(w0-1) -> B3 -> enL3(t<128) -> B4 -> combine.
// ---------------------------------------------------------------------------
__global__ __launch_bounds__(512, 2) void k_fused(
    const float* __restrict__ rs, const float* __restrict__ xs,
    const float* __restrict__ coords,
    const float* __restrict__ eb1, const float* __restrict__ ew2,
    const float* __restrict__ eb2, const float* __restrict__ ew3,
    const float* __restrict__ eb3, const float* __restrict__ nb1,
    const float* __restrict__ nb2, const float* __restrict__ nb3,
    const float* __restrict__ nw3, const _Float16* __restrict__ wsp,
    float* __restrict__ out)
{
    __shared__ alignas(16) _Float16 xs_h[N_ * 256];     // 16384 B, swizzled
    __shared__ alignas(16) _Float16 ew1T_s[48 * 256];   // 24576 B, swizzled
    __shared__ alignas(16) _Float16 h1e[16 * HEP];      //  3072 B
    __shared__ alignas(16) float    h2e[16 * 26];       //  1664 B
    __shared__ alignas(16) float    eb1_s[48];          // eb1*log2e, padded
    __shared__ alignas(16) float    b2_s[16];           // eb2*log2e, padded
    __shared__ float rs_s[96], nw3_s[200], nb2_s[32], nb3_s[8], co_s[24];
    __shared__ float bfn_s[48], cut_s[16], bfe_s[48];

    const int bid = blockIdx.x;
    const int b = bid >> 1, rbase = (bid & 1) << 4;     // this block's i-rows
    const int t = threadIdx.x;
    const int wv = t >> 6, l = t & 63, quad = l >> 4, c = l & 15;

    const _Float16* ew1T_g = wsp;
    const _Float16* nw1T_g = wsp + 48 * 256;
    const _Float16* nw2T_g = wsp + 48 * 256 + 96 * 256;

    // ---- issue ew1T DMA: 24576 B = 3 rounds x (512 lanes x 16 B) ----
    {
        const char* g = (const char*)ew1T_g;
        char* d = (char*)ew1T_s;
        const int wb = wv * 1024;
        #pragma unroll
        for (int r = 0; r < 3; ++r)
            lds_dma16(d + r * 8192 + wb, g + r * 8192 + wb + (l << 4));
    }
    // ---- stage xs[b] fp32 -> swizzled f16 (2 x 16B blocks per thread) ----
    {
        const float4* src = (const float4*)(xs + (size_t)b * N_ * D_);
        #pragma unroll
        for (int u = 0; u < 2; ++u) {
            const int idx = t + 512 * u;                // 1024 = 32 rows x 32 kb
            const int row = idx >> 5, kb = idx & 31;
            float4 v0 = src[idx << 1];
            float4 v1 = src[(idx << 1) + 1];
            union { _Float16 h[8]; uint4 q; } pk;
            pk.h[0] = (_Float16)v0.x; pk.h[1] = (_Float16)v0.y;
            pk.h[2] = (_Float16)v0.z; pk.h[3] = (_Float16)v0.w;
            pk.h[4] = (_Float16)v1.x; pk.h[5] = (_Float16)v1.y;
            pk.h[6] = (_Float16)v1.z; pk.h[7] = (_Float16)v1.w;
            *(uint4*)&xs_h[row * 256 + ((kb ^ (row & 7)) << 3)] = pk.q;
        }
    }
    // ---- misc small stages ----
    if (t < 96)  rs_s[t] = rs[b * 96 + t];
    if (t < 200) nw3_s[t] = nw3[t] * LN2f;
    if (t < N2)  nb2_s[t] = nb2[t] * L2Ef;
    if (t < N3)  nb3_s[t] = nb3[t];
    if (t < 24)  co_s[t] = coords[t];
    if (t < 48)  eb1_s[t] = (t < E1) ? eb1[t] * L2Ef : 0.f;
    if (t < 16)  b2_s[t] = (t < E2) ? eb2[t] * L2Ef : 0.f;
    if (t < 384) ((uint64_t*)h1e)[t] = 0ull;            // zero k-pad cols 81..95

    // ---- per-lane register constants (global reads, independent of LDS) ----
    f16x4 b2fT[3];
    #pragma unroll
    for (int Nt = 0; Nt < 3; ++Nt) {
        f16x4 p;
        #pragma unroll
        for (int r = 0; r < 4; ++r) {
            const int n = Nt * 16 + quad * 4 + r;
            p[r] = (_Float16)((n < E1 && c < E2) ? ew2[n * E2 + c] : 0.f);
        }
        b2fT[Nt] = p;
    }
    float w3q[4];
    #pragma unroll
    for (int r = 0; r < 4; ++r) {
        const int m = quad * 4 + r;
        w3q[r] = (m < E2) ? ew3[m] * LN2f : 0.f;
    }
    const float eb3v = eb3[0];

    __syncthreads();   // B1: xs_h + ew1T_s (DMA drained) + misc ready

    // ---- phase A part 1: en L1 (waves 0-5, B direct from L2) -------------
    if (wv < 6) {
        const int n_col = wv * 16 + c;                  // neuron (0..95)
        const float nb1v = (n_col < N1) ? nb1[n_col] * L2Ef : 0.f;
        const _Float16* bg = nw1T_g + n_col * 256 + quad * 8;
        f32x4 acc1 = (f32x4){0.f, 0.f, 0.f, 0.f};
        f16x8 Bp = *(const f16x8*)bg;
        #pragma unroll
        for (int Kt = 0; Kt < 8; ++Kt) {
            f16x8 Bf = Bp;
            if (Kt < 7) Bp = *(const f16x8*)(bg + (Kt + 1) * 32);
            f16x8 A = *(const f16x8*)&xs_h[(rbase + c) * 256 +
                                           (((Kt * 4 + quad) ^ (c & 7)) << 3)];
            acc1 = MFMA32(A, Bf, acc1);
        }
        if (n_col < N1) {
            #pragma unroll
            for (int r2 = 0; r2 < 4; ++r2)
                h1e[(quad * 4 + r2) * HEP + n_col] = (_Float16)ssp2(acc1[r2] + nb1v);
        }
    }

    // ---- phase A part 2: fused ee, both i-rows (lr = wv, wv+8) -----------
    // Per K-step: iv0,iv1,jv0,jv1 + 3x b1 = 7 ds_read_b128 for 12 MFMA
    // (was 12 reads across two separate rounds). i0&7 == i1&7 == wv.
    {
        const int i0 = rbase + wv, i1 = i0 + 8;
        f32x4 acc[2][2][3];                    // [ih][h][Nt]
        #pragma unroll
        for (int Nt = 0; Nt < 3; ++Nt) {
            f32x4 bias = *(const f32x4*)&eb1_s[Nt * 16 + quad * 4];
            acc[0][0][Nt] = bias; acc[0][1][Nt] = bias;
            acc[1][0][Nt] = bias; acc[1][1][Nt] = bias;
        }
        #pragma unroll
        for (int Kt = 0; Kt < 8; ++Kt) {
            const int kb = Kt * 4 + quad;
            const int sj = (kb ^ (c & 7)) << 3;
            const int si = (kb ^ wv) << 3;
            f16x8 iv0 = *(const f16x8*)&xs_h[i0 * 256 + si];
            f16x8 iv1 = *(const f16x8*)&xs_h[i1 * 256 + si];
            f16x8 jv0 = *(const f16x8*)&xs_h[c * 256 + sj];
            f16x8 jv1 = *(const f16x8*)&xs_h[(16 + c) * 256 + sj];
            f16x8 P00 = iv0 * jv0;             // B-operand: B[k][j=c]
            f16x8 P01 = iv0 * jv1;
            f16x8 P10 = iv1 * jv0;
            f16x8 P11 = iv1 * jv1;
            #pragma unroll
            for (int Nt = 0; Nt < 3; ++Nt) {
                f16x8 b1 = *(const f16x8*)&ew1T_s[(Nt * 16 + c) * 256 + sj];
                acc[0][0][Nt] = MFMA32(b1, P00, acc[0][0][Nt]);
                acc[0][1][Nt] = MFMA32(b1, P01, acc[0][1][Nt]);
                acc[1][0][Nt] = MFMA32(b1, P10, acc[1][0][Nt]);
                acc[1][1][Nt] = MFMA32(b1, P11, acc[1][1][Nt]);
            }
        }
        // epilogue per i-row: act -> pack -> MFMA16 x3 -> act -> reduce
        const f32x4 b2i = *(const f32x4*)&b2_s[quad * 4];
        #pragma unroll
        for (int ih = 0; ih < 2; ++ih) {
            const int lr = wv + ih * 8, i = rbase + lr;
            const float rix = rs_s[i * 3 + 0], riy = rs_s[i * 3 + 1],
                        riz = rs_s[i * 3 + 2];
            float cxi = 0.f, cyi = 0.f, czi = 0.f;
            #pragma unroll
            for (int h = 0; h < 2; ++h) {
                f32x4 acc2 = b2i;
                #pragma unroll
                for (int Nt = 0; Nt < 3; ++Nt) {
                    f16x4 bh_;
                    #pragma unroll
                    for (int r2 = 0; r2 < 4; ++r2)
                        bh_[r2] = (_Float16)ssp2(acc[ih][h][Nt][r2]);
                    acc2 = MFMA16(b2fT[Nt], bh_, acc2);
                }
                float wsum = 0.f;
                #pragma unroll
                for (int r2 = 0; r2 < 4; ++r2)
                    wsum = fmaf(w3q[r2], ssp2(acc2[r2]), wsum);
                wsum += __shfl_xor(wsum, 16);
                wsum += __shfl_xor(wsum, 32);  // allreduce over quads (m)
                const float wj = wsum + eb3v;
                const int j = c + 16 * h;
                cxi = fmaf(wj, rix - rs_s[j * 3 + 0], cxi);
                cyi = fmaf(wj, riy - rs_s[j * 3 + 1], cyi);
                czi = fmaf(wj, riz - rs_s[j * 3 + 2], czi);
            }
            #pragma unroll
            for (int m2 = 1; m2 < 16; m2 <<= 1) {
                cxi += __shfl_xor(cxi, m2);
                cyi += __shfl_xor(cyi, m2);
                czi += __shfl_xor(czi, m2);
            }
            if (l == 0) {
                bfe_s[lr * 3 + 0] = cxi;
                bfe_s[lr * 3 + 1] = cyi;
                bfe_s[lr * 3 + 2] = czi;
            }
        }
    }
    __syncthreads();   // B2: h1e done, ee done

    // ---- phase B: en L2 (waves 0-1, B direct from L2) --------------------
    if (wv < 2) {
        const int n = wv * 16 + c;                      // 0..31
        const _Float16* bg2 = nw2T_g + n * 96 + quad * 8;
        f32x4 acc2 = (f32x4){0.f, 0.f, 0.f, 0.f};
        #pragma unroll
        for (int Kt2 = 0; Kt2 < 3; ++Kt2) {
            f16x8 A  = *(const f16x8*)&h1e[c * HEP + Kt2 * 32 + quad * 8];
            f16x8 Bf = *(const f16x8*)(bg2 + Kt2 * 32);
            acc2 = MFMA32(A, Bf, acc2);
        }
        if (n < N2) {
            #pragma unroll
            for (int r2 = 0; r2 < 4; ++r2)
                h2e[(quad * 4 + r2) * 26 + n] = ssp2(acc2[r2] + nb2_s[n]);
        }
    }
    __syncthreads();   // B3: h2e ready

    // ---- phase C: en L3 + bf_nuc + cutoff (threads 0..127) ---------------
    if (t < 128) {
        const int r = t >> 3, s = t & 7;
        const int gi = rbase + r;
        float w = nb3_s[s];
        const int rb26 = r * 26;
        #pragma unroll
        for (int kk = 0; kk < N2; ++kk)
            w = fmaf(h2e[rb26 + kk], nw3_s[kk * N3 + s], w);
        const float dx = rs_s[gi * 3 + 0] - co_s[s * 3 + 0];
        const float dy = rs_s[gi * 3 + 1] - co_s[s * 3 + 1];
        const float dz = rs_s[gi * 3 + 2] - co_s[s * 3 + 2];
        float cx = w * dx, cy = w * dy, cz = w * dz;
        #pragma unroll
        for (int m2 = 1; m2 < 8; m2 <<= 1) {
            cx += __shfl_xor(cx, m2);
            cy += __shfl_xor(cy, m2);
            cz += __shfl_xor(cz, m2);
        }
        const float rr  = sqrtf(dx * dx + dy * dy + dz * dz);
        const float xsc = 2.f * rr;            // r / L, L = 0.5
        float cf = (xsc < 0.5f) ? xsc * xsc * (6.f - 8.f * xsc + 3.f * xsc * xsc) : 1.f;
        #pragma unroll
        for (int m2 = 1; m2 < 8; m2 <<= 1) cf *= __shfl_xor(cf, m2);
        if (s == 0) {
            bfn_s[r * 3 + 0] = cx;
            bfn_s[r * 3 + 1] = cy;
            bfn_s[r * 3 + 2] = cz;
            cut_s[r] = cf;
        }
    }
    __syncthreads();   // B4: bfn_s/cut_s ready

    // ---- final combine + store (threads 0..47: this block's 16 rows) -----
    if (t < 48) {
        const int r = t / 3;
        out[(size_t)b * (N_ * 3) + rbase * 3 + t] =
            rs_s[rbase * 3 + t] + 1e-4f * cut_s[r] * (bfe_s[t] + bfn_s[t]);
    }
}

extern "C" void kernel_launch(void* const* d_in, const int* in_sizes, int n_in,
                              void* d_out, int out_size, void* d_ws, size_t ws_size,
                              hipStream_t stream)
{
    const float* rs     = (const float*)d_in[0];
    const float* xs     = (const float*)d_in[1];
    const float* coords = (const float*)d_in[2];
    const float* ew1    = (const float*)d_in[3];
    const float* eb1    = (const float*)d_in[4];
    const float* ew2    = (const float*)d_in[5];
    const float* eb2    = (const float*)d_in[6];
    const float* ew3    = (const float*)d_in[7];
    const float* eb3    = (const float*)d_in[8];
    const float* nw1    = (const float*)d_in[9];
    const float* nb1    = (const float*)d_in[10];
    const float* nw2    = (const float*)d_in[11];
    const float* nb2    = (const float*)d_in[12];
    const float* nw3    = (const float*)d_in[13];
    const float* nb3    = (const float*)d_in[14];

    _Float16* wsp = (_Float16*)d_ws;   // 79,872 B used

    k_prep<<<20, 256, 0, stream>>>(ew1, nw1, nw2, wsp);
    k_fused<<<B_ * 2, 512, 0, stream>>>(rs, xs, coords, eb1, ew2, eb2, ew3, eb3,
                                        nb1, nb2, nb3, nw3, wsp, (float*)d_out);
}